// Round 1
// baseline (658.706 us; speedup 1.0000x reference)
//
#include <hip/hip_runtime.h>
#include <hip/hip_bf16.h>
#include <stdint.h>

#define Bz 8
#define Tz 2048
#define Cz 768
#define Hz 12
#define Dz 64
#define Mz (Bz*Tz)          // 16384
#define N3 (3*Cz)           // 2304
#define YSZ ((size_t)Mz*Cz) // 12582912

typedef __bf16 bf16;
typedef __attribute__((ext_vector_type(8))) bf16 bf16x8;
typedef __attribute__((ext_vector_type(4))) bf16 bf16x4;
typedef __attribute__((ext_vector_type(4))) float f32x4;

#define MFMA(A_,B_,C_) __builtin_amdgcn_mfma_f32_16x16x32_bf16(A_,B_,C_,0,0,0)

__device__ __forceinline__ void gll16(const void* g, void* l) {
  __builtin_amdgcn_global_load_lds(
      (const __attribute__((address_space(1))) void*)g,
      (__attribute__((address_space(3))) void*)l, 16, 0, 0);
}

// ---------------- prep: x fp32 -> bf16 ----------------
__global__ __launch_bounds__(256) void prep_x(const float* __restrict__ x,
                                              bf16* __restrict__ xb) {
  int i = blockIdx.x*blockDim.x + threadIdx.x;
  int stride = gridDim.x*blockDim.x;
  const float4* x4 = (const float4*)x;
  int n4 = (int)(YSZ/4);
  for (int j = i; j < n4; j += stride) {
    float4 f = x4[j];
    bf16x4 o = { (bf16)f.x, (bf16)f.y, (bf16)f.z, (bf16)f.w };
    *(bf16x4*)(xb + 4*(size_t)j) = o;
  }
}

// ---------------- prep: transpose+convert W [R][Ncol] f32 -> Wt [Ncol][R] bf16 ----------------
__global__ __launch_bounds__(256) void transpose_conv(const float* __restrict__ src,
                                                      bf16* __restrict__ dst,
                                                      int R, int Ncol) {
  __shared__ float tile[32][33];
  int bx = blockIdx.x;  // col tile of src
  int by = blockIdx.y;  // row tile of src
  int tx = threadIdx.x & 31, ty = threadIdx.x >> 5;
  #pragma unroll
  for (int i = 0; i < 4; ++i)
    tile[ty + 8*i][tx] = src[(size_t)(by*32 + ty + 8*i)*Ncol + bx*32 + tx];
  __syncthreads();
  #pragma unroll
  for (int i = 0; i < 4; ++i)
    dst[(size_t)(bx*32 + ty + 8*i)*R + by*32 + tx] = (bf16)tile[tx][ty + 8*i];
}

// ---------------- GEMM: C[M,N] = A[M,K] * Bt[N,K]^T  (m97 structure) ----------------
// EPI 0: qkv epilogue (scatter q->ws bf16, k,v->d_out f32, +b_attn)
// EPI 1: proj epilogue (y f32 + b_proj)
template<int EPI>
__global__ __launch_bounds__(256) void gemm128(
    const bf16* __restrict__ A, const bf16* __restrict__ Bt,
    int Kdim, int Mtiles, int Ntiles,
    const float* __restrict__ bias,
    bf16* __restrict__ qws, float* __restrict__ kout, float* __restrict__ vout,
    float* __restrict__ yout)
{
  __shared__ alignas(16) bf16 sA[128*32];
  __shared__ alignas(16) bf16 sB[128*32];
  int nwg = Mtiles*Ntiles;
  int bid = blockIdx.x;
  int cpx = nwg >> 3;                       // nwg % 8 == 0 for our launches
  int swz = (bid & 7)*cpx + (bid >> 3);
  int mtile = swz % Mtiles, ntile = swz / Mtiles;
  int tid = threadIdx.x, w = tid >> 6, l = tid & 63;
  int wr = w >> 1, wc = w & 1;
  const int rowBase = mtile*128, colBase = ntile*128;

  f32x4 acc[4][4] = {};

  // staging addresses: wave w covers LDS rows [w*32, w*32+32)
  int srow = w*32 + (l >> 2);
  int skoff = (l & 3)*8;
  const bf16* gA = A + (size_t)(rowBase + srow)*Kdim + skoff;
  const bf16* gB = Bt + (size_t)(colBase + srow)*Kdim + skoff;
  bf16* lA = sA + w*1024;
  bf16* lB = sB + w*1024;

  int lr = l & 15, lk = (l >> 4)*8;

  for (int k0 = 0; k0 < Kdim; k0 += 32) {
    gll16(gA,                 lA);
    gll16(gA + (size_t)16*Kdim, lA + 512);
    gll16(gB,                 lB);
    gll16(gB + (size_t)16*Kdim, lB + 512);
    gA += 32; gB += 32;
    __syncthreads();
    bf16x8 af[4], bfr[4];
    #pragma unroll
    for (int m = 0; m < 4; ++m)
      af[m] = *(const bf16x8*)(sA + (size_t)(wr*64 + m*16 + lr)*32 + lk);
    #pragma unroll
    for (int n = 0; n < 4; ++n)
      bfr[n] = *(const bf16x8*)(sB + (size_t)(wc*64 + n*16 + lr)*32 + lk);
    #pragma unroll
    for (int m = 0; m < 4; ++m)
      #pragma unroll
      for (int n = 0; n < 4; ++n)
        acc[m][n] = MFMA(af[m], bfr[n], acc[m][n]);
    __syncthreads();
  }

  #pragma unroll
  for (int m = 0; m < 4; ++m) {
    #pragma unroll
    for (int n = 0; n < 4; ++n) {
      int gcol = colBase + wc*64 + n*16 + lr;
      float bv = bias[gcol];
      #pragma unroll
      for (int r = 0; r < 4; ++r) {
        int grow = rowBase + wr*64 + m*16 + (l >> 4)*4 + r;
        float v = acc[m][n][r] + bv;
        if (EPI == 0) {
          int which = gcol / Cz;
          int within = gcol - which*Cz;
          int h = within >> 6, d = within & 63;
          size_t idx = (((size_t)(grow >> 11)*Hz + h)*Tz + (grow & 2047))*Dz + d;
          if (which == 0)      qws[idx] = (bf16)v;
          else if (which == 1) kout[idx] = v;
          else                 vout[idx] = v;
        } else {
          yout[(size_t)grow*Cz + gcol] = v;
        }
      }
    }
  }
}

// ---------------- flash attention (causal), QBLK=64, 4 waves x 16 rows ----------------
#define SCL 0.18033688011112042f  // log2(e) / sqrt(64)

__global__ __launch_bounds__(256) void attn64(
    const bf16* __restrict__ qws, const float* __restrict__ kg,
    const float* __restrict__ vg, bf16* __restrict__ yatt)
{
  __shared__ alignas(16) bf16 sK[64][88];
  __shared__ alignas(16) bf16 sVt[64][88];
  __shared__ alignas(16) bf16 sP[4][16][88];
  int qb = blockIdx.x;        // q tile: rows [qb*64, qb*64+64)
  int bh = blockIdx.y;        // 0..95
  int b = bh / Hz, h = bh - b*Hz;
  int tid = threadIdx.x, w = tid >> 6, l = tid & 63;
  int lr = l & 15, lg = l >> 4;
  const int q0 = qb*64;

  // Q fragments (held whole block)
  const bf16* qbase = qws + ((size_t)bh*Tz + q0 + w*16 + lr)*Dz + lg*8;
  bf16x8 qf0 = *(const bf16x8*)qbase;
  bf16x8 qf1 = *(const bf16x8*)(qbase + 32);

  f32x4 o[4] = {};
  float mrun[4] = {-1e30f,-1e30f,-1e30f,-1e30f};
  float lrun[4] = {0.f,0.f,0.f,0.f};

  const float* kbase = kg + (size_t)bh*Tz*Dz;
  const float* vbase = vg + (size_t)bh*Tz*Dz;

  for (int kt = 0; kt <= qb; ++kt) {
    int kv0 = kt*64;
    // stage K -> sK[kv][d] bf16; V -> sVt[d][kv] bf16 (transposed)
    {
      int kvr = tid >> 4;
      int d4 = (tid & 15)*4;
      #pragma unroll
      for (int i = 0; i < 4; ++i) {
        int kv = i*16 + kvr;
        const float4 fk = *(const float4*)(kbase + (size_t)(kv0+kv)*Dz + d4);
        const float4 fv = *(const float4*)(vbase + (size_t)(kv0+kv)*Dz + d4);
        bf16x4 pk = {(bf16)fk.x,(bf16)fk.y,(bf16)fk.z,(bf16)fk.w};
        *(bf16x4*)(&sK[kv][d4]) = pk;
        sVt[d4+0][kv] = (bf16)fv.x;
        sVt[d4+1][kv] = (bf16)fv.y;
        sVt[d4+2][kv] = (bf16)fv.z;
        sVt[d4+3][kv] = (bf16)fv.w;
      }
    }
    __syncthreads();

    // S = Q K^T  (per wave: 16 q-rows x 64 kv-cols)
    f32x4 s[4] = {};
    #pragma unroll
    for (int n = 0; n < 4; ++n) {
      bf16x8 kf0 = *(const bf16x8*)(&sK[n*16 + lr][lg*8]);
      bf16x8 kf1 = *(const bf16x8*)(&sK[n*16 + lr][lg*8 + 32]);
      s[n] = MFMA(qf0, kf0, s[n]);
      s[n] = MFMA(qf1, kf1, s[n]);
    }

    // online softmax (exp2 domain, scale folded into SCL)
    int qrow = q0 + w*16 + lg*4;
    float pv[4][4];
    #pragma unroll
    for (int r = 0; r < 4; ++r) {
      float mx = -1e30f;
      #pragma unroll
      for (int n = 0; n < 4; ++n) {
        float sv = s[n][r]*SCL;
        int kcol = kv0 + n*16 + lr;
        sv = (kcol <= qrow + r) ? sv : -1e30f;
        pv[n][r] = sv;
        mx = fmaxf(mx, sv);
      }
      mx = fmaxf(mx, __shfl_xor(mx, 1));
      mx = fmaxf(mx, __shfl_xor(mx, 2));
      mx = fmaxf(mx, __shfl_xor(mx, 4));
      mx = fmaxf(mx, __shfl_xor(mx, 8));
      float mnew = fmaxf(mrun[r], mx);
      float corr = exp2f(mrun[r] - mnew);
      mrun[r] = mnew;
      float rs = 0.f;
      #pragma unroll
      for (int n = 0; n < 4; ++n) {
        float e = exp2f(pv[n][r] - mnew);
        pv[n][r] = e;
        rs += e;
      }
      rs += __shfl_xor(rs, 1);
      rs += __shfl_xor(rs, 2);
      rs += __shfl_xor(rs, 4);
      rs += __shfl_xor(rs, 8);
      lrun[r] = lrun[r]*corr + rs;
      #pragma unroll
      for (int n = 0; n < 4; ++n) o[n][r] *= corr;
    }

    // P -> A-fragment layout via per-wave LDS transpose
    #pragma unroll
    for (int n = 0; n < 4; ++n)
      #pragma unroll
      for (int r = 0; r < 4; ++r)
        sP[w][lg*4 + r][n*16 + lr] = (bf16)pv[n][r];

    bf16x8 pf0 = *(const bf16x8*)(&sP[w][lr][lg*8]);
    bf16x8 pf1 = *(const bf16x8*)(&sP[w][lr][lg*8 + 32]);

    // O += P V
    #pragma unroll
    for (int n = 0; n < 4; ++n) {
      bf16x8 vf0 = *(const bf16x8*)(&sVt[n*16 + lr][lg*8]);
      bf16x8 vf1 = *(const bf16x8*)(&sVt[n*16 + lr][lg*8 + 32]);
      o[n] = MFMA(pf0, vf0, o[n]);
      o[n] = MFMA(pf1, vf1, o[n]);
    }
    __syncthreads();
  }

  // write y_att [B,T,H,D] bf16
  #pragma unroll
  for (int n = 0; n < 4; ++n) {
    #pragma unroll
    for (int r = 0; r < 4; ++r) {
      int t = q0 + w*16 + lg*4 + r;
      int d = n*16 + lr;
      yatt[((size_t)(b*Tz + t))*Cz + h*Dz + d] = (bf16)(o[n][r] / lrun[r]);
    }
  }
}

// ---------------- launch ----------------
extern "C" void kernel_launch(void* const* d_in, const int* in_sizes, int n_in,
                              void* d_out, int out_size, void* d_ws, size_t ws_size,
                              hipStream_t stream) {
  const float* x      = (const float*)d_in[0];
  const float* w_attn = (const float*)d_in[1];
  const float* b_attn = (const float*)d_in[2];
  const float* w_proj = (const float*)d_in[3];
  const float* b_proj = (const float*)d_in[4];

  float* y    = (float*)d_out;
  float* kout = y + YSZ;
  float* vout = y + 2*YSZ;

  char* ws = (char*)d_ws;
  bf16* xb   = (bf16*)ws;                    // 25165824 B  (reused as yatt)
  bf16* qws  = (bf16*)(ws + 25165824);       // 25165824 B
  bf16* wtA  = (bf16*)(ws + 50331648);       // 3538944 B
  bf16* wtP  = (bf16*)(ws + 53870592);       // 1179648 B
  bf16* yatt = xb;

  prep_x<<<2048, 256, 0, stream>>>(x, xb);
  transpose_conv<<<dim3(N3/32, Cz/32), 256, 0, stream>>>(w_attn, wtA, Cz, N3);
  transpose_conv<<<dim3(Cz/32, Cz/32), 256, 0, stream>>>(w_proj, wtP, Cz, Cz);

  gemm128<0><<<dim3((Mz/128)*(N3/128)), 256, 0, stream>>>(
      xb, wtA, Cz, Mz/128, N3/128, b_attn, qws, kout, vout, nullptr);

  attn64<<<dim3(Tz/64, Bz*Hz), 256, 0, stream>>>(qws, kout, vout, yatt);

  gemm128<1><<<dim3((Mz/128)*(Cz/128)), 256, 0, stream>>>(
      yatt, wtP, Cz, Mz/128, Cz/128, b_proj, nullptr, nullptr, nullptr, y);
}

// Round 3
// 572.340 us; speedup vs baseline: 1.1509x; 1.1509x over previous
//
#include <hip/hip_runtime.h>
#include <hip/hip_bf16.h>
#include <stdint.h>

#define Bz 8
#define Tz 2048
#define Cz 768
#define Hz 12
#define Dz 64
#define Mz (Bz*Tz)          // 16384
#define N3 (3*Cz)           // 2304
#define YSZ ((size_t)Mz*Cz) // 12582912

typedef __bf16 bf16;
typedef __attribute__((ext_vector_type(8))) bf16 bf16x8;
typedef __attribute__((ext_vector_type(4))) bf16 bf16x4;
typedef __attribute__((ext_vector_type(4))) float f32x4;

#define MFMA(A_,B_,C_) __builtin_amdgcn_mfma_f32_16x16x32_bf16(A_,B_,C_,0,0,0)

__device__ __forceinline__ void gll16(const void* g, void* l) {
  __builtin_amdgcn_global_load_lds(
      (const __attribute__((address_space(1))) void*)g,
      (__attribute__((address_space(3))) void*)l, 16, 0, 0);
}

// ---------------- prep: x fp32 -> bf16 ----------------
__global__ __launch_bounds__(256) void prep_x(const float* __restrict__ x,
                                              bf16* __restrict__ xb) {
  int i = blockIdx.x*blockDim.x + threadIdx.x;
  int stride = gridDim.x*blockDim.x;
  const float4* x4 = (const float4*)x;
  int n4 = (int)(YSZ/4);
  for (int j = i; j < n4; j += stride) {
    float4 f = x4[j];
    bf16x4 o = { (bf16)f.x, (bf16)f.y, (bf16)f.z, (bf16)f.w };
    *(bf16x4*)(xb + 4*(size_t)j) = o;
  }
}

// ---------------- prep: transpose+convert W [R][Ncol] f32 -> Wt [Ncol][R] bf16 ----------------
__global__ __launch_bounds__(256) void transpose_conv(const float* __restrict__ src,
                                                      bf16* __restrict__ dst,
                                                      int R, int Ncol) {
  __shared__ float tile[32][33];
  int bx = blockIdx.x, by = blockIdx.y;
  int tx = threadIdx.x & 31, ty = threadIdx.x >> 5;
  #pragma unroll
  for (int i = 0; i < 4; ++i)
    tile[ty + 8*i][tx] = src[(size_t)(by*32 + ty + 8*i)*Ncol + bx*32 + tx];
  __syncthreads();
  #pragma unroll
  for (int i = 0; i < 4; ++i)
    dst[(size_t)(bx*32 + ty + 8*i)*R + by*32 + tx] = (bf16)tile[tx][ty + 8*i];
}

// ---------------- V transpose: vout f32 [BH][T][D] -> vtb bf16 [BH][D][T] ----------------
__global__ __launch_bounds__(256) void vtrans(const float* __restrict__ v,
                                              bf16* __restrict__ vt) {
  __shared__ float tl[64][65];
  int tb = blockIdx.x, bh = blockIdx.y;
  const float* src = v + ((size_t)bh*Tz + tb*64)*Dz;
  int tr = threadIdx.x >> 4;
  int c4 = (threadIdx.x & 15)*4;
  #pragma unroll
  for (int i = 0; i < 4; ++i) {
    float4 f = *(const float4*)(src + (size_t)(i*16 + tr)*Dz + c4);
    tl[i*16 + tr][c4+0] = f.x; tl[i*16 + tr][c4+1] = f.y;
    tl[i*16 + tr][c4+2] = f.z; tl[i*16 + tr][c4+3] = f.w;
  }
  __syncthreads();
  bf16* dst = vt + (size_t)bh*Dz*Tz + tb*64;
  #pragma unroll
  for (int i = 0; i < 4; ++i) {
    int d = i*16 + tr;
    bf16x4 o = { (bf16)tl[c4+0][d], (bf16)tl[c4+1][d],
                 (bf16)tl[c4+2][d], (bf16)tl[c4+3][d] };
    *(bf16x4*)(dst + (size_t)d*Tz + c4) = o;
  }
}

// ---------------- GEMM: C[M,N] = A[M,K] * Bt[N,K]^T  (m97 structure) ----------------
template<int EPI>
__global__ __launch_bounds__(256) void gemm128(
    const bf16* __restrict__ A, const bf16* __restrict__ Bt,
    int Kdim, int Mtiles, int Ntiles,
    const float* __restrict__ bias,
    bf16* __restrict__ qws, bf16* __restrict__ kws,
    float* __restrict__ kout, float* __restrict__ vout,
    float* __restrict__ yout)
{
  __shared__ alignas(16) bf16 sA[128*32];
  __shared__ alignas(16) bf16 sB[128*32];
  int nwg = Mtiles*Ntiles;
  int bid = blockIdx.x;
  int cpx = nwg >> 3;
  int swz = (bid & 7)*cpx + (bid >> 3);
  int mtile = swz % Mtiles, ntile = swz / Mtiles;
  int tid = threadIdx.x, w = tid >> 6, l = tid & 63;
  int wr = w >> 1, wc = w & 1;
  const int rowBase = mtile*128, colBase = ntile*128;

  f32x4 acc[4][4] = {};

  int srow = w*32 + (l >> 2);
  int skoff = (l & 3)*8;
  const bf16* gA = A + (size_t)(rowBase + srow)*Kdim + skoff;
  const bf16* gB = Bt + (size_t)(colBase + srow)*Kdim + skoff;
  bf16* lA = sA + w*1024;
  bf16* lB = sB + w*1024;

  int lr = l & 15, lk = (l >> 4)*8;

  for (int k0 = 0; k0 < Kdim; k0 += 32) {
    gll16(gA,                   lA);
    gll16(gA + (size_t)16*Kdim, lA + 512);
    gll16(gB,                   lB);
    gll16(gB + (size_t)16*Kdim, lB + 512);
    gA += 32; gB += 32;
    __syncthreads();
    bf16x8 af[4], bfr[4];
    #pragma unroll
    for (int m = 0; m < 4; ++m)
      af[m] = *(const bf16x8*)(sA + (size_t)(wr*64 + m*16 + lr)*32 + lk);
    #pragma unroll
    for (int n = 0; n < 4; ++n)
      bfr[n] = *(const bf16x8*)(sB + (size_t)(wc*64 + n*16 + lr)*32 + lk);
    #pragma unroll
    for (int m = 0; m < 4; ++m)
      #pragma unroll
      for (int n = 0; n < 4; ++n)
        acc[m][n] = MFMA(af[m], bfr[n], acc[m][n]);
    __syncthreads();
  }

  #pragma unroll
  for (int m = 0; m < 4; ++m) {
    #pragma unroll
    for (int n = 0; n < 4; ++n) {
      int gcol = colBase + wc*64 + n*16 + lr;
      float bv = bias[gcol];
      #pragma unroll
      for (int r = 0; r < 4; ++r) {
        int grow = rowBase + wr*64 + m*16 + (l >> 4)*4 + r;
        float v = acc[m][n][r] + bv;
        if (EPI == 0) {
          int which = gcol / Cz;
          int within = gcol - which*Cz;
          int h = within >> 6, d = within & 63;
          size_t idx = (((size_t)(grow >> 11)*Hz + h)*Tz + (grow & 2047))*Dz + d;
          if (which == 0)      qws[idx] = (bf16)v;
          else if (which == 1) { kout[idx] = v; kws[idx] = (bf16)v; }
          else                 vout[idx] = v;
        } else {
          yout[(size_t)grow*Cz + gcol] = v;
        }
      }
    }
  }
}

// ---------------- flash attention (causal), QB=64, KVB=128, 4 waves x 16 rows ----------------
#define SCL 0.18033688011112042f  // log2(e) / sqrt(64)
#define KVB 128

__global__ __launch_bounds__(256) void attn128(
    const bf16* __restrict__ qws, const bf16* __restrict__ kb,
    const bf16* __restrict__ vtb, bf16* __restrict__ yatt)
{
  __shared__ alignas(16) bf16 sK[KVB*64];    // [kv][d] row 128B, chunk ^= row&7
  __shared__ alignas(16) bf16 sVt[64*KVB];   // [d][t]  row 256B, chunk ^= row&15
  __shared__ alignas(16) bf16 sP[4*16*128];  // per-wave [q16][kv128], chunk ^= (q&7)
  int qb = gridDim.x - 1 - blockIdx.x;       // big tiles first
  int bh = blockIdx.y;
  int b = bh / Hz, h = bh - b*Hz;
  int tid = threadIdx.x, w = tid >> 6, l = tid & 63;
  int lr = l & 15, lg = l >> 4;
  const int q0 = qb*64;
  const f32x4 zf = {0.f, 0.f, 0.f, 0.f};

  const bf16* qbase = qws + ((size_t)bh*Tz + q0 + w*16 + lr)*Dz + lg*8;
  bf16x8 qf0 = *(const bf16x8*)qbase;
  bf16x8 qf1 = *(const bf16x8*)(qbase + 32);

  f32x4 o[4] = {};
  float mrun[4] = {-1e30f,-1e30f,-1e30f,-1e30f};
  float lrun[4] = {0.f,0.f,0.f,0.f};

  const bf16* kgb = kb  + (size_t)bh*Tz*Dz;
  const bf16* vgb = vtb + (size_t)bh*Dz*Tz;
  bf16* sPw = sP + w*2048;

  int nT = (qb + 2) >> 1;
  for (int kt = 0; kt < nT; ++kt) {
    int kv0 = kt*KVB;
    // ---- stage K (16KB) + Vt (16KB) via global_load_lds, pre-swizzled source ----
    #pragma unroll
    for (int p = 0; p < 4; ++p) {
      int off = p*4096 + tid*16;
      int krow = off >> 7, kch = (off >> 4) & 7;
      gll16(kgb + (size_t)(kv0 + krow)*Dz + ((kch ^ (krow & 7)) << 3),
            (char*)sK + p*4096 + w*1024);
      int vrow = off >> 8, vch = (off >> 4) & 15;
      gll16(vgb + (size_t)vrow*Tz + kv0 + ((vch ^ (vrow & 15)) << 3),
            (char*)sVt + p*4096 + w*1024);
    }
    __syncthreads();

    int qminw = q0 + w*16;
    int qmaxw = qminw + 15;
    f32x4 s[8];
    #pragma unroll
    for (int n = 0; n < 8; ++n) {
      int kvb = kv0 + n*16;
      if (kvb <= qmaxw) {
        int row = n*16 + lr;
        int c0 = lg ^ (lr & 7);
        bf16x8 kf0 = *(const bf16x8*)((const char*)sK + row*128 + (c0 << 4));
        bf16x8 kf1 = *(const bf16x8*)((const char*)sK + row*128 + ((c0 ^ 4) << 4));
        f32x4 t = MFMA(qf0, kf0, zf);
        s[n] = MFMA(qf1, kf1, t);
      } else {
        s[n][0] = -1e30f; s[n][1] = -1e30f; s[n][2] = -1e30f; s[n][3] = -1e30f;
      }
    }
    // scale + causal mask
    #pragma unroll
    for (int n = 0; n < 8; ++n) {
      int kvb = kv0 + n*16;
      if (kvb <= qmaxw) {
        if (kvb + 15 > qminw) {
          #pragma unroll
          for (int r = 0; r < 4; ++r) {
            int qrow = qminw + lg*4 + r;
            float sv = s[n][r]*SCL;
            s[n][r] = (kvb + lr <= qrow) ? sv : -1e30f;
          }
        } else {
          #pragma unroll
          for (int r = 0; r < 4; ++r) s[n][r] *= SCL;
        }
      }
    }
    // online softmax per q-row
    #pragma unroll
    for (int r = 0; r < 4; ++r) {
      float mx = s[0][r];
      #pragma unroll
      for (int n = 1; n < 8; ++n) mx = fmaxf(mx, s[n][r]);
      mx = fmaxf(mx, __shfl_xor(mx, 1));
      mx = fmaxf(mx, __shfl_xor(mx, 2));
      mx = fmaxf(mx, __shfl_xor(mx, 4));
      mx = fmaxf(mx, __shfl_xor(mx, 8));
      float mnew = fmaxf(mrun[r], mx);
      float corr = exp2f(mrun[r] - mnew);
      mrun[r] = mnew;
      float rs = 0.f;
      #pragma unroll
      for (int n = 0; n < 8; ++n) {
        float e = exp2f(s[n][r] - mnew);
        s[n][r] = e;
        rs += e;
      }
      rs += __shfl_xor(rs, 1);
      rs += __shfl_xor(rs, 2);
      rs += __shfl_xor(rs, 4);
      rs += __shfl_xor(rs, 8);
      lrun[r] = lrun[r]*corr + rs;
      #pragma unroll
      for (int nd = 0; nd < 4; ++nd) o[nd][r] *= corr;
    }
    // store P (bf16) swizzled: elem q*128 + (c ^ ((q&7)<<3))
    #pragma unroll
    for (int n = 0; n < 8; ++n) {
      #pragma unroll
      for (int r = 0; r < 4; ++r) {
        int q = lg*4 + r;
        sPw[q*128 + ((n*16 + lr) ^ ((q & 7) << 3))] = (bf16)s[n][r];
      }
    }
    // O += P V
    #pragma unroll
    for (int kk = 0; kk < 4; ++kk) {
      bf16x8 pf = *(const bf16x8*)(sPw + lr*128 + ((kk*32 + lg*8) ^ ((lr & 7) << 3)));
      #pragma unroll
      for (int nd = 0; nd < 4; ++nd) {
        int row = nd*16 + lr;
        int cv = (kk*4 + lg) ^ lr;
        bf16x8 vf = *(const bf16x8*)((const char*)sVt + row*256 + (cv << 4));
        o[nd] = MFMA(pf, vf, o[nd]);
      }
    }
    __syncthreads();
  }

  float invl[4];
  #pragma unroll
  for (int r = 0; r < 4; ++r) invl[r] = 1.0f / lrun[r];
  #pragma unroll
  for (int nd = 0; nd < 4; ++nd) {
    #pragma unroll
    for (int r = 0; r < 4; ++r) {
      int t = q0 + w*16 + lg*4 + r;
      int d = nd*16 + lr;
      yatt[((size_t)(b*Tz + t))*Cz + h*Dz + d] = (bf16)(o[nd][r]*invl[r]);
    }
  }
}

// ---------------- launch ----------------
extern "C" void kernel_launch(void* const* d_in, const int* in_sizes, int n_in,
                              void* d_out, int out_size, void* d_ws, size_t ws_size,
                              hipStream_t stream) {
  const float* x      = (const float*)d_in[0];
  const float* w_attn = (const float*)d_in[1];
  const float* b_attn = (const float*)d_in[2];
  const float* w_proj = (const float*)d_in[3];
  const float* b_proj = (const float*)d_in[4];

  float* y    = (float*)d_out;
  float* kout = y + YSZ;
  float* vout = y + 2*YSZ;

  char* ws = (char*)d_ws;
  bf16* xb   = (bf16*)ws;                     // 25165824 B (reused as yatt)
  bf16* qws  = (bf16*)(ws + 25165824);        // 25165824 B
  bf16* kb   = (bf16*)(ws + 50331648);        // 25165824 B
  bf16* vtb  = (bf16*)(ws + 75497472);        // 25165824 B
  bf16* wtA  = (bf16*)(ws + 100663296);       // 3538944 B
  bf16* wtP  = (bf16*)(ws + 104202240);       // 1179648 B
  bf16* yatt = xb;

  prep_x<<<2048, 256, 0, stream>>>(x, xb);
  transpose_conv<<<dim3(N3/32, Cz/32), 256, 0, stream>>>(w_attn, wtA, Cz, N3);
  transpose_conv<<<dim3(Cz/32, Cz/32), 256, 0, stream>>>(w_proj, wtP, Cz, Cz);

  gemm128<0><<<dim3((Mz/128)*(N3/128)), 256, 0, stream>>>(
      xb, wtA, Cz, Mz/128, N3/128, b_attn, qws, kb, kout, vout, nullptr);

  vtrans<<<dim3(Tz/64, Bz*Hz), 256, 0, stream>>>(vout, vtb);

  attn128<<<dim3(Tz/64, Bz*Hz), 256, 0, stream>>>(qws, kb, vtb, yatt);

  gemm128<1><<<dim3((Mz/128)*(Cz/128)), 256, 0, stream>>>(
      yatt, wtP, Cz, Mz/128, Cz/128, b_proj, nullptr, nullptr, nullptr, nullptr, y);
}

// Round 4
// 510.550 us; speedup vs baseline: 1.2902x; 1.1210x over previous
//
#include <hip/hip_runtime.h>
#include <hip/hip_bf16.h>
#include <stdint.h>

#define Bz 8
#define Tz 2048
#define Cz 768
#define Hz 12
#define Dz 64
#define Mz (Bz*Tz)          // 16384
#define N3 (3*Cz)           // 2304
#define YSZ ((size_t)Mz*Cz) // 12582912

#define SCL 0.18033688011112042f  // log2(e) / sqrt(64)
#define KVB 128

typedef __bf16 bf16;
typedef __attribute__((ext_vector_type(8))) bf16 bf16x8;
typedef __attribute__((ext_vector_type(4))) bf16 bf16x4;
typedef __attribute__((ext_vector_type(4))) float f32x4;

#define MFMA(A_,B_,C_) __builtin_amdgcn_mfma_f32_16x16x32_bf16(A_,B_,C_,0,0,0)

__device__ __forceinline__ void gll16(const void* g, void* l) {
  __builtin_amdgcn_global_load_lds(
      (const __attribute__((address_space(1))) void*)g,
      (__attribute__((address_space(3))) void*)l, 16, 0, 0);
}

// ---------------- prep: x fp32 -> bf16 ----------------
__global__ __launch_bounds__(256) void prep_x(const float* __restrict__ x,
                                              bf16* __restrict__ xb) {
  int i = blockIdx.x*blockDim.x + threadIdx.x;
  int stride = gridDim.x*blockDim.x;
  const float4* x4 = (const float4*)x;
  int n4 = (int)(YSZ/4);
  for (int j = i; j < n4; j += stride) {
    float4 f = x4[j];
    bf16x4 o = { (bf16)f.x, (bf16)f.y, (bf16)f.z, (bf16)f.w };
    *(bf16x4*)(xb + 4*(size_t)j) = o;
  }
}

// ---------------- prep: transpose+convert W [R][Ncol] f32 -> Wt [Ncol][R] bf16 ----------------
__global__ __launch_bounds__(256) void transpose_conv(const float* __restrict__ src,
                                                      bf16* __restrict__ dst,
                                                      int R, int Ncol) {
  __shared__ float tile[32][33];
  int bx = blockIdx.x, by = blockIdx.y;
  int tx = threadIdx.x & 31, ty = threadIdx.x >> 5;
  #pragma unroll
  for (int i = 0; i < 4; ++i)
    tile[ty + 8*i][tx] = src[(size_t)(by*32 + ty + 8*i)*Ncol + bx*32 + tx];
  __syncthreads();
  #pragma unroll
  for (int i = 0; i < 4; ++i)
    dst[(size_t)(bx*32 + ty + 8*i)*R + by*32 + tx] = (bf16)tile[tx][ty + 8*i];
}

// ---------------- V transpose: vout f32 [BH][T][D] -> vtb bf16 [BH][D][T] ----------------
__global__ __launch_bounds__(256) void vtrans(const float* __restrict__ v,
                                              bf16* __restrict__ vt) {
  __shared__ float tl[64][65];
  int tb = blockIdx.x, bh = blockIdx.y;
  const float* src = v + ((size_t)bh*Tz + tb*64)*Dz;
  int tr = threadIdx.x >> 4;
  int c4 = (threadIdx.x & 15)*4;
  #pragma unroll
  for (int i = 0; i < 4; ++i) {
    float4 f = *(const float4*)(src + (size_t)(i*16 + tr)*Dz + c4);
    tl[i*16 + tr][c4+0] = f.x; tl[i*16 + tr][c4+1] = f.y;
    tl[i*16 + tr][c4+2] = f.z; tl[i*16 + tr][c4+3] = f.w;
  }
  __syncthreads();
  bf16* dst = vt + (size_t)bh*Dz*Tz + tb*64;
  #pragma unroll
  for (int i = 0; i < 4; ++i) {
    int d = i*16 + tr;
    bf16x4 o = { (bf16)tl[c4+0][d], (bf16)tl[c4+1][d],
                 (bf16)tl[c4+2][d], (bf16)tl[c4+3][d] };
    *(bf16x4*)(dst + (size_t)d*Tz + c4) = o;
  }
}

// ---------------- GEMM: C[M,N] = A[M,K] * Bt[N,K]^T  (m97 structure) ----------------
template<int EPI>
__global__ __launch_bounds__(256) void gemm128(
    const bf16* __restrict__ A, const bf16* __restrict__ Bt,
    int Kdim, int Mtiles, int Ntiles,
    const float* __restrict__ bias,
    bf16* __restrict__ qws, bf16* __restrict__ kws,
    float* __restrict__ kout, float* __restrict__ vout,
    float* __restrict__ yout)
{
  __shared__ alignas(16) bf16 sA[128*32];
  __shared__ alignas(16) bf16 sB[128*32];
  int nwg = Mtiles*Ntiles;
  int bid = blockIdx.x;
  int cpx = nwg >> 3;
  int swz = (bid & 7)*cpx + (bid >> 3);
  int mtile = swz % Mtiles, ntile = swz / Mtiles;
  int tid = threadIdx.x, w = tid >> 6, l = tid & 63;
  int wr = w >> 1, wc = w & 1;
  const int rowBase = mtile*128, colBase = ntile*128;

  f32x4 acc[4][4] = {};

  int srow = w*32 + (l >> 2);
  int skoff = (l & 3)*8;
  const bf16* gA = A + (size_t)(rowBase + srow)*Kdim + skoff;
  const bf16* gB = Bt + (size_t)(colBase + srow)*Kdim + skoff;
  bf16* lA = sA + w*1024;
  bf16* lB = sB + w*1024;

  int lr = l & 15, lk = (l >> 4)*8;

  for (int k0 = 0; k0 < Kdim; k0 += 32) {
    gll16(gA,                   lA);
    gll16(gA + (size_t)16*Kdim, lA + 512);
    gll16(gB,                   lB);
    gll16(gB + (size_t)16*Kdim, lB + 512);
    gA += 32; gB += 32;
    __syncthreads();
    bf16x8 af[4], bfr[4];
    #pragma unroll
    for (int m = 0; m < 4; ++m)
      af[m] = *(const bf16x8*)(sA + (size_t)(wr*64 + m*16 + lr)*32 + lk);
    #pragma unroll
    for (int n = 0; n < 4; ++n)
      bfr[n] = *(const bf16x8*)(sB + (size_t)(wc*64 + n*16 + lr)*32 + lk);
    #pragma unroll
    for (int m = 0; m < 4; ++m)
      #pragma unroll
      for (int n = 0; n < 4; ++n)
        acc[m][n] = MFMA(af[m], bfr[n], acc[m][n]);
    __syncthreads();
  }

  #pragma unroll
  for (int m = 0; m < 4; ++m) {
    #pragma unroll
    for (int n = 0; n < 4; ++n) {
      int gcol = colBase + wc*64 + n*16 + lr;
      float bv = bias[gcol];
      #pragma unroll
      for (int r = 0; r < 4; ++r) {
        int grow = rowBase + wr*64 + m*16 + (l >> 4)*4 + r;
        float v = acc[m][n][r] + bv;
        if (EPI == 0) {
          int which = gcol / Cz;
          int within = gcol - which*Cz;
          int h = within >> 6, d = within & 63;
          size_t idx = (((size_t)(grow >> 11)*Hz + h)*Tz + (grow & 2047))*Dz + d;
          if (which == 0)      qws[idx] = (bf16)(v * SCL);   // pre-scale q
          else if (which == 1) { kout[idx] = v; kws[idx] = (bf16)v; }
          else                 vout[idx] = v;
        } else {
          yout[(size_t)grow*Cz + gcol] = v;
        }
      }
    }
  }
}

// ---------------- flash attention (causal), swapped-QK, dbuf, defer-max ----------------
__device__ __forceinline__ void stageKV(const bf16* kgb, const bf16* vgb, int kv0,
                                        char* cK, char* cV, int tid, int w) {
  #pragma unroll
  for (int p = 0; p < 4; ++p) {
    int off = p*4096 + tid*16;
    int krow = off >> 7, kch = (off >> 4) & 7;
    gll16(kgb + (size_t)(kv0 + krow)*Dz + ((kch ^ (krow & 7)) << 3),
          cK + p*4096 + w*1024);
    int vrow = off >> 8, vch = (off >> 4) & 15;
    gll16(vgb + (size_t)vrow*Tz + kv0 + ((vch ^ (vrow & 15)) << 3),
          cV + p*4096 + w*1024);
  }
}

__device__ __forceinline__ void attn_tile(
    int kv0, int qminw, int qmaxw, int q_l, int lr, int lg,
    const char* cK, const char* cV, char* sPw,
    const bf16x8& qf0, const bf16x8& qf1,
    f32x4 (&o)[4], float& mrun, float& lrun)
{
  const f32x4 zf = {0.f, 0.f, 0.f, 0.f};
  f32x4 s[8];
  // S^T[kv][q] = K * Q^T  (swapped): lane owns q = q_l, kv = kv0 + n*16 + 4*lg + r
  #pragma unroll
  for (int n = 0; n < 8; ++n) {
    int kvb = kv0 + n*16;
    if (kvb <= qmaxw) {
      int row = n*16 + lr;
      int c0 = lg ^ (lr & 7);
      bf16x8 kf0 = *(const bf16x8*)(cK + row*128 + (c0 << 4));
      bf16x8 kf1 = *(const bf16x8*)(cK + row*128 + ((c0 ^ 4) << 4));
      f32x4 t = MFMA(kf0, qf0, zf);
      s[n] = MFMA(kf1, qf1, t);
    } else {
      s[n][0] = -1e30f; s[n][1] = -1e30f; s[n][2] = -1e30f; s[n][3] = -1e30f;
    }
  }
  // causal mask (diag blocks only; scale pre-folded into Q)
  #pragma unroll
  for (int n = 0; n < 8; ++n) {
    int kvb = kv0 + n*16;
    if (kvb <= qmaxw && kvb + 15 > qminw) {
      #pragma unroll
      for (int r = 0; r < 4; ++r)
        s[n][r] = (kvb + 4*lg + r <= q_l) ? s[n][r] : -1e30f;
    }
  }
  // in-lane max tree + 2 shfl
  f32x4 a0, a1;
  #pragma unroll
  for (int r = 0; r < 4; ++r) {
    a0[r] = fmaxf(fmaxf(s[0][r], s[1][r]), fmaxf(s[2][r], s[3][r]));
    a1[r] = fmaxf(fmaxf(s[4][r], s[5][r]), fmaxf(s[6][r], s[7][r]));
  }
  float mx = fmaxf(fmaxf(fmaxf(a0[0], a0[1]), fmaxf(a0[2], a0[3])),
                   fmaxf(fmaxf(a1[0], a1[1]), fmaxf(a1[2], a1[3])));
  mx = fmaxf(mx, __shfl_xor(mx, 16));
  mx = fmaxf(mx, __shfl_xor(mx, 32));

  bool skip = __all(mx <= mrun + 8.0f);
  float corr = 1.0f;
  if (!skip) {
    float mnew = fmaxf(mrun, mx);
    corr = exp2f(mrun - mnew);
    mrun = mnew;
  }
  f32x4 acc4 = zf;
  #pragma unroll
  for (int n = 0; n < 8; ++n) {
    #pragma unroll
    for (int r = 0; r < 4; ++r) {
      float e = exp2f(s[n][r] - mrun);
      s[n][r] = e;
      acc4[r] += e;
    }
  }
  float rs = (acc4[0] + acc4[1]) + (acc4[2] + acc4[3]);
  rs += __shfl_xor(rs, 16);
  rs += __shfl_xor(rs, 32);
  if (!skip) {
    lrun = lrun*corr + rs;
    float c0_ = __shfl(corr, 4*lg + 0);
    float c1_ = __shfl(corr, 4*lg + 1);
    float c2_ = __shfl(corr, 4*lg + 2);
    float c3_ = __shfl(corr, 4*lg + 3);
    #pragma unroll
    for (int nd = 0; nd < 4; ++nd) {
      o[nd][0] *= c0_; o[nd][1] *= c1_; o[nd][2] *= c2_; o[nd][3] *= c3_;
    }
  } else {
    lrun += rs;
  }
  // P store: 8x ds_write_b64, swizzled [q=lr][kv], block b = kv>>3, b ^= lr
  #pragma unroll
  for (int n = 0; n < 8; ++n) {
    bf16x4 pk = { (bf16)s[n][0], (bf16)s[n][1], (bf16)s[n][2], (bf16)s[n][3] };
    int b = n*2 + (lg >> 1);
    *(bf16x4*)(sPw + lr*256 + ((b ^ lr) << 4) + ((lg & 1) << 3)) = pk;
  }
  // O += P V
  #pragma unroll
  for (int kk = 0; kk < 4; ++kk) {
    if (kv0 + kk*32 <= qmaxw) {
      int cb = (kk*4 + lg) ^ lr;
      bf16x8 pf = *(const bf16x8*)(sPw + lr*256 + (cb << 4));
      #pragma unroll
      for (int nd = 0; nd < 4; ++nd) {
        bf16x8 vf = *(const bf16x8*)(cV + (nd*16 + lr)*256 + (cb << 4));
        o[nd] = MFMA(pf, vf, o[nd]);
      }
    }
  }
}

__global__ __launch_bounds__(256) void attn128(
    const bf16* __restrict__ qws, const bf16* __restrict__ kb,
    const bf16* __restrict__ vtb, bf16* __restrict__ yatt)
{
  __shared__ alignas(16) char sK[2][16384];   // [kv][d] 128B rows, chunk ^= row&7
  __shared__ alignas(16) char sV[2][16384];   // [d][t] 256B rows, chunk ^= row&15
  __shared__ alignas(16) char sP[4][4096];    // per-wave P^T
  int qb = gridDim.x - 1 - blockIdx.x;
  int bh = blockIdx.y;
  int b = bh / Hz, h = bh - b*Hz;
  int tid = threadIdx.x, w = tid >> 6, l = tid & 63;
  int lr = l & 15, lg = l >> 4;
  const int q0 = qb*64;
  const int qminw = q0 + w*16;
  const int qmaxw = qminw + 15;
  const int q_l = qminw + lr;

  const bf16* qbase = qws + ((size_t)bh*Tz + qminw + lr)*Dz + lg*8;
  bf16x8 qf0 = *(const bf16x8*)qbase;
  bf16x8 qf1 = *(const bf16x8*)(qbase + 32);

  f32x4 o[4] = {};
  float mrun = -1e30f, lrun = 0.f;

  const bf16* kgb = kb  + (size_t)bh*Tz*Dz;
  const bf16* vgb = vtb + (size_t)bh*Dz*Tz;
  char* sPw = sP[w];

  int nT = (qb + 2) >> 1;
  stageKV(kgb, vgb, 0, sK[0], sV[0], tid, w);
  int buf = 0;
  for (int kt = 0; kt + 1 < nT; ++kt) {
    stageKV(kgb, vgb, (kt + 1)*KVB, sK[buf ^ 1], sV[buf ^ 1], tid, w);
    asm volatile("s_waitcnt vmcnt(8)" ::: "memory");
    __builtin_amdgcn_s_barrier();
    __builtin_amdgcn_sched_barrier(0);
    attn_tile(kt*KVB, qminw, qmaxw, q_l, lr, lg, sK[buf], sV[buf], sPw,
              qf0, qf1, o, mrun, lrun);
    asm volatile("s_waitcnt lgkmcnt(0)" ::: "memory");
    __builtin_amdgcn_s_barrier();
    __builtin_amdgcn_sched_barrier(0);
    buf ^= 1;
  }
  asm volatile("s_waitcnt vmcnt(0)" ::: "memory");
  __builtin_amdgcn_s_barrier();
  __builtin_amdgcn_sched_barrier(0);
  attn_tile((nT - 1)*KVB, qminw, qmaxw, q_l, lr, lg, sK[buf], sV[buf], sPw,
            qf0, qf1, o, mrun, lrun);

  float inv = 1.0f / lrun;
  float i0 = __shfl(inv, 4*lg + 0);
  float i1 = __shfl(inv, 4*lg + 1);
  float i2 = __shfl(inv, 4*lg + 2);
  float i3 = __shfl(inv, 4*lg + 3);
  #pragma unroll
  for (int nd = 0; nd < 4; ++nd) {
    int d = nd*16 + lr;
    int t0 = q0 + w*16 + lg*4;
    bf16* yp = yatt + ((size_t)(b*Tz + t0))*Cz + h*Dz + d;
    yp[0*Cz]   = (bf16)(o[nd][0] * i0);
    yp[1*Cz]   = (bf16)(o[nd][1] * i1);
    yp[2*Cz]   = (bf16)(o[nd][2] * i2);
    yp[3*Cz]   = (bf16)(o[nd][3] * i3);
  }
}

// ---------------- launch ----------------
extern "C" void kernel_launch(void* const* d_in, const int* in_sizes, int n_in,
                              void* d_out, int out_size, void* d_ws, size_t ws_size,
                              hipStream_t stream) {
  const float* x      = (const float*)d_in[0];
  const float* w_attn = (const float*)d_in[1];
  const float* b_attn = (const float*)d_in[2];
  const float* w_proj = (const float*)d_in[3];
  const float* b_proj = (const float*)d_in[4];

  float* y    = (float*)d_out;
  float* kout = y + YSZ;
  float* vout = y + 2*YSZ;

  char* ws = (char*)d_ws;
  bf16* xb   = (bf16*)ws;                     // 25165824 B (reused as yatt)
  bf16* qws  = (bf16*)(ws + 25165824);        // 25165824 B
  bf16* kb   = (bf16*)(ws + 50331648);        // 25165824 B
  bf16* vtb  = (bf16*)(ws + 75497472);        // 25165824 B
  bf16* wtA  = (bf16*)(ws + 100663296);       // 3538944 B
  bf16* wtP  = (bf16*)(ws + 104202240);       // 1179648 B
  bf16* yatt = xb;

  prep_x<<<2048, 256, 0, stream>>>(x, xb);
  transpose_conv<<<dim3(N3/32, Cz/32), 256, 0, stream>>>(w_attn, wtA, Cz, N3);
  transpose_conv<<<dim3(Cz/32, Cz/32), 256, 0, stream>>>(w_proj, wtP, Cz, Cz);

  gemm128<0><<<dim3((Mz/128)*(N3/128)), 256, 0, stream>>>(
      xb, wtA, Cz, Mz/128, N3/128, b_attn, qws, kb, kout, vout, nullptr);

  vtrans<<<dim3(Tz/64, Bz*Hz), 256, 0, stream>>>(vout, vtb);

  attn128<<<dim3(Tz/64, Bz*Hz), 256, 0, stream>>>(qws, kb, vtb, yatt);

  gemm128<1><<<dim3((Mz/128)*(Cz/128)), 256, 0, stream>>>(
      yatt, wtP, Cz, Mz/128, Cz/128, b_proj, nullptr, nullptr, nullptr, nullptr, y);
}

// Round 5
// 416.102 us; speedup vs baseline: 1.5830x; 1.2270x over previous
//
#include <hip/hip_runtime.h>
#include <hip/hip_bf16.h>
#include <stdint.h>

#define Bz 8
#define Tz 2048
#define Cz 768
#define Hz 12
#define Dz 64
#define Mz (Bz*Tz)          // 16384
#define N3 (3*Cz)           // 2304
#define YSZ ((size_t)Mz*Cz) // 12582912

#define SCL 0.18033688011112042f  // log2(e) / sqrt(64)
#define KVB 64

typedef __bf16 bf16;
typedef __attribute__((ext_vector_type(8))) bf16 bf16x8;
typedef __attribute__((ext_vector_type(4))) bf16 bf16x4;
typedef __attribute__((ext_vector_type(4))) float f32x4;

#define MFMA(A_,B_,C_) __builtin_amdgcn_mfma_f32_16x16x32_bf16(A_,B_,C_,0,0,0)

__device__ __forceinline__ void gll16(const void* g, void* l) {
  __builtin_amdgcn_global_load_lds(
      (const __attribute__((address_space(1))) void*)g,
      (__attribute__((address_space(3))) void*)l, 16, 0, 0);
}

// ---------------- prep: x fp32 -> bf16 ----------------
__global__ __launch_bounds__(256) void prep_x(const float* __restrict__ x,
                                              bf16* __restrict__ xb) {
  int i = blockIdx.x*blockDim.x + threadIdx.x;
  int stride = gridDim.x*blockDim.x;
  const float4* x4 = (const float4*)x;
  int n4 = (int)(YSZ/4);
  for (int j = i; j < n4; j += stride) {
    float4 f = x4[j];
    bf16x4 o = { (bf16)f.x, (bf16)f.y, (bf16)f.z, (bf16)f.w };
    *(bf16x4*)(xb + 4*(size_t)j) = o;
  }
}

// ---------------- prep: transpose+convert W [R][Ncol] f32 -> Wt [Ncol][R] bf16 ----------------
__global__ __launch_bounds__(256) void transpose_conv(const float* __restrict__ src,
                                                      bf16* __restrict__ dst,
                                                      int R, int Ncol) {
  __shared__ float tile[32][33];
  int bx = blockIdx.x, by = blockIdx.y;
  int tx = threadIdx.x & 31, ty = threadIdx.x >> 5;
  #pragma unroll
  for (int i = 0; i < 4; ++i)
    tile[ty + 8*i][tx] = src[(size_t)(by*32 + ty + 8*i)*Ncol + bx*32 + tx];
  __syncthreads();
  #pragma unroll
  for (int i = 0; i < 4; ++i)
    dst[(size_t)(bx*32 + ty + 8*i)*R + by*32 + tx] = (bf16)tile[tx][ty + 8*i];
}

// ---------------- V transpose: vout f32 [BH][T][D] -> vtb bf16 [BH][D][T] ----------------
__global__ __launch_bounds__(256) void vtrans(const float* __restrict__ v,
                                              bf16* __restrict__ vt) {
  __shared__ float tl[64][65];
  int tb = blockIdx.x, bh = blockIdx.y;
  const float* src = v + ((size_t)bh*Tz + tb*64)*Dz;
  int tr = threadIdx.x >> 4;
  int c4 = (threadIdx.x & 15)*4;
  #pragma unroll
  for (int i = 0; i < 4; ++i) {
    float4 f = *(const float4*)(src + (size_t)(i*16 + tr)*Dz + c4);
    tl[i*16 + tr][c4+0] = f.x; tl[i*16 + tr][c4+1] = f.y;
    tl[i*16 + tr][c4+2] = f.z; tl[i*16 + tr][c4+3] = f.w;
  }
  __syncthreads();
  bf16* dst = vt + (size_t)bh*Dz*Tz + tb*64;
  #pragma unroll
  for (int i = 0; i < 4; ++i) {
    int d = i*16 + tr;
    bf16x4 o = { (bf16)tl[c4+0][d], (bf16)tl[c4+1][d],
                 (bf16)tl[c4+2][d], (bf16)tl[c4+3][d] };
    *(bf16x4*)(dst + (size_t)d*Tz + c4) = o;
  }
}

// ---------------- GEMM: C[M,N] = A[M,K] * Bt[N,K]^T  (m97 structure) ----------------
template<int EPI>
__global__ __launch_bounds__(256) void gemm128(
    const bf16* __restrict__ A, const bf16* __restrict__ Bt,
    int Kdim, int Mtiles, int Ntiles,
    const float* __restrict__ bias,
    bf16* __restrict__ qws, bf16* __restrict__ kws,
    float* __restrict__ kout, float* __restrict__ vout,
    float* __restrict__ yout)
{
  __shared__ alignas(16) bf16 sA[128*32];
  __shared__ alignas(16) bf16 sB[128*32];
  int nwg = Mtiles*Ntiles;
  int bid = blockIdx.x;
  int cpx = nwg >> 3;
  int swz = (bid & 7)*cpx + (bid >> 3);
  int mtile = swz % Mtiles, ntile = swz / Mtiles;
  int tid = threadIdx.x, w = tid >> 6, l = tid & 63;
  int wr = w >> 1, wc = w & 1;
  const int rowBase = mtile*128, colBase = ntile*128;

  f32x4 acc[4][4] = {};

  int srow = w*32 + (l >> 2);
  int skoff = (l & 3)*8;
  const bf16* gA = A + (size_t)(rowBase + srow)*Kdim + skoff;
  const bf16* gB = Bt + (size_t)(colBase + srow)*Kdim + skoff;
  bf16* lA = sA + w*1024;
  bf16* lB = sB + w*1024;

  int lr = l & 15, lk = (l >> 4)*8;

  for (int k0 = 0; k0 < Kdim; k0 += 32) {
    gll16(gA,                   lA);
    gll16(gA + (size_t)16*Kdim, lA + 512);
    gll16(gB,                   lB);
    gll16(gB + (size_t)16*Kdim, lB + 512);
    gA += 32; gB += 32;
    __syncthreads();
    bf16x8 af[4], bfr[4];
    #pragma unroll
    for (int m = 0; m < 4; ++m)
      af[m] = *(const bf16x8*)(sA + (size_t)(wr*64 + m*16 + lr)*32 + lk);
    #pragma unroll
    for (int n = 0; n < 4; ++n)
      bfr[n] = *(const bf16x8*)(sB + (size_t)(wc*64 + n*16 + lr)*32 + lk);
    #pragma unroll
    for (int m = 0; m < 4; ++m)
      #pragma unroll
      for (int n = 0; n < 4; ++n)
        acc[m][n] = MFMA(af[m], bfr[n], acc[m][n]);
    __syncthreads();
  }

  #pragma unroll
  for (int m = 0; m < 4; ++m) {
    #pragma unroll
    for (int n = 0; n < 4; ++n) {
      int gcol = colBase + wc*64 + n*16 + lr;
      float bv = bias[gcol];
      #pragma unroll
      for (int r = 0; r < 4; ++r) {
        int grow = rowBase + wr*64 + m*16 + (l >> 4)*4 + r;
        float v = acc[m][n][r] + bv;
        if (EPI == 0) {
          int which = gcol / Cz;
          int within = gcol - which*Cz;
          int h = within >> 6, d = within & 63;
          size_t idx = (((size_t)(grow >> 11)*Hz + h)*Tz + (grow & 2047))*Dz + d;
          if (which == 0)      qws[idx] = (bf16)(v * SCL);   // pre-scale q
          else if (which == 1) { kout[idx] = v; kws[idx] = (bf16)v; }
          else                 vout[idx] = v;
        } else {
          yout[(size_t)grow*Cz + gcol] = v;
        }
      }
    }
  }
}

// ---------------- flash attention (causal), KVB=64, 4 blocks/CU ----------------
__device__ __forceinline__ void stageKV(const bf16* kgb, const bf16* vgb, int kv0,
                                        char* cK, char* cV, int tid, int w) {
  #pragma unroll
  for (int p = 0; p < 2; ++p) {
    int off = p*4096 + tid*16;
    int row = off >> 7, ch = (off >> 4) & 7;
    int sw = ((ch ^ (row & 7)) << 3);
    gll16(kgb + (size_t)(kv0 + row)*Dz + sw, cK + p*4096 + w*1024);
    gll16(vgb + (size_t)row*Tz + kv0 + sw,   cV + p*4096 + w*1024);
  }
}

__device__ __forceinline__ void attn_tile(
    int kv0, int qminw, int qmaxw, int q_l, int lr, int lg,
    const char* cK, const char* cV, char* sPw,
    const bf16x8& qf0, const bf16x8& qf1,
    f32x4 (&o)[4], float& mrun, float& lrun)
{
  const f32x4 zf = {0.f, 0.f, 0.f, 0.f};
  f32x4 s[4];
  // S^T[kv][q] = K * Q^T (swapped): lane owns q=q_l, kv = kv0 + n*16 + 4*lg + r
  __builtin_amdgcn_s_setprio(1);
  #pragma unroll
  for (int n = 0; n < 4; ++n) {
    int kvb = kv0 + n*16;
    if (kvb <= qmaxw) {
      int row = n*16 + lr;
      int c0 = lg ^ (lr & 7);
      bf16x8 kf0 = *(const bf16x8*)(cK + row*128 + (c0 << 4));
      bf16x8 kf1 = *(const bf16x8*)(cK + row*128 + ((c0 ^ 4) << 4));
      f32x4 t = MFMA(kf0, qf0, zf);
      s[n] = MFMA(kf1, qf1, t);
    } else {
      s[n][0] = -1e30f; s[n][1] = -1e30f; s[n][2] = -1e30f; s[n][3] = -1e30f;
    }
  }
  __builtin_amdgcn_s_setprio(0);
  // causal mask (diag blocks only; scale pre-folded into Q)
  #pragma unroll
  for (int n = 0; n < 4; ++n) {
    int kvb = kv0 + n*16;
    if (kvb <= qmaxw && kvb + 15 > qminw) {
      #pragma unroll
      for (int r = 0; r < 4; ++r)
        s[n][r] = (kvb + 4*lg + r <= q_l) ? s[n][r] : -1e30f;
    }
  }
  // in-lane max tree + 2 shfl
  f32x4 a0;
  #pragma unroll
  for (int r = 0; r < 4; ++r)
    a0[r] = fmaxf(fmaxf(s[0][r], s[1][r]), fmaxf(s[2][r], s[3][r]));
  float mx = fmaxf(fmaxf(a0[0], a0[1]), fmaxf(a0[2], a0[3]));
  mx = fmaxf(mx, __shfl_xor(mx, 16));
  mx = fmaxf(mx, __shfl_xor(mx, 32));

  bool skip = __all(mx <= mrun + 8.0f);
  float corr = 1.0f;
  if (!skip) {
    float mnew = fmaxf(mrun, mx);
    corr = exp2f(mrun - mnew);
    mrun = mnew;
  }
  f32x4 acc4 = zf;
  #pragma unroll
  for (int n = 0; n < 4; ++n) {
    #pragma unroll
    for (int r = 0; r < 4; ++r) {
      float e = exp2f(s[n][r] - mrun);
      s[n][r] = e;
      acc4[r] += e;
    }
  }
  float rs = (acc4[0] + acc4[1]) + (acc4[2] + acc4[3]);
  rs += __shfl_xor(rs, 16);
  rs += __shfl_xor(rs, 32);
  if (!skip) {
    lrun = lrun*corr + rs;
    float c0_ = __shfl(corr, 4*lg + 0);
    float c1_ = __shfl(corr, 4*lg + 1);
    float c2_ = __shfl(corr, 4*lg + 2);
    float c3_ = __shfl(corr, 4*lg + 3);
    #pragma unroll
    for (int nd = 0; nd < 4; ++nd) {
      o[nd][0] *= c0_; o[nd][1] *= c1_; o[nd][2] *= c2_; o[nd][3] *= c3_;
    }
  } else {
    lrun += rs;
  }
  // P store: [q=lr][kv] rows of 128B, chunk b ^= lr&7
  #pragma unroll
  for (int n = 0; n < 4; ++n) {
    bf16x4 pk = { (bf16)s[n][0], (bf16)s[n][1], (bf16)s[n][2], (bf16)s[n][3] };
    int b = n*2 + (lg >> 1);
    *(bf16x4*)(sPw + lr*128 + ((b ^ (lr & 7)) << 4) + ((lg & 1) << 3)) = pk;
  }
  // O += P V
  __builtin_amdgcn_s_setprio(1);
  #pragma unroll
  for (int kk = 0; kk < 2; ++kk) {
    if (kv0 + kk*32 <= qmaxw) {
      int cb = (kk*4 + lg) ^ (lr & 7);
      bf16x8 pf = *(const bf16x8*)(sPw + lr*128 + (cb << 4));
      #pragma unroll
      for (int nd = 0; nd < 4; ++nd) {
        bf16x8 vf = *(const bf16x8*)(cV + (nd*16 + lr)*128 + (cb << 4));
        o[nd] = MFMA(pf, vf, o[nd]);
      }
    }
  }
  __builtin_amdgcn_s_setprio(0);
}

__global__ __launch_bounds__(256, 4) void attn128(
    const bf16* __restrict__ qws, const bf16* __restrict__ kb,
    const bf16* __restrict__ vtb, bf16* __restrict__ yatt)
{
  __shared__ alignas(16) char sK[2][8192];   // [kv][d] 128B rows, chunk ^= row&7
  __shared__ alignas(16) char sV[2][8192];   // [d][t]  128B rows, chunk ^= row&7
  __shared__ alignas(16) char sP[4][2048];   // per-wave P^T
  int qb = gridDim.x - 1 - blockIdx.x;
  int bh = blockIdx.y;
  int b = bh / Hz, h = bh - b*Hz;
  int tid = threadIdx.x, w = tid >> 6, l = tid & 63;
  int lr = l & 15, lg = l >> 4;
  const int q0 = qb*64;
  const int qminw = q0 + w*16;
  const int qmaxw = qminw + 15;
  const int q_l = qminw + lr;

  const bf16* qbase = qws + ((size_t)bh*Tz + qminw + lr)*Dz + lg*8;
  bf16x8 qf0 = *(const bf16x8*)qbase;
  bf16x8 qf1 = *(const bf16x8*)(qbase + 32);

  f32x4 o[4] = {};
  float mrun = -1e30f, lrun = 0.f;

  const bf16* kgb = kb  + (size_t)bh*Tz*Dz;
  const bf16* vgb = vtb + (size_t)bh*Dz*Tz;
  char* sPw = sP[w];

  int nT = qb + 1;
  stageKV(kgb, vgb, 0, sK[0], sV[0], tid, w);
  int buf = 0;
  for (int kt = 0; kt + 1 < nT; ++kt) {
    stageKV(kgb, vgb, (kt + 1)*KVB, sK[buf ^ 1], sV[buf ^ 1], tid, w);
    asm volatile("s_waitcnt vmcnt(4)" ::: "memory");
    __builtin_amdgcn_s_barrier();
    __builtin_amdgcn_sched_barrier(0);
    attn_tile(kt*KVB, qminw, qmaxw, q_l, lr, lg, sK[buf], sV[buf], sPw,
              qf0, qf1, o, mrun, lrun);
    asm volatile("s_waitcnt lgkmcnt(0)" ::: "memory");
    __builtin_amdgcn_s_barrier();
    __builtin_amdgcn_sched_barrier(0);
    buf ^= 1;
  }
  asm volatile("s_waitcnt vmcnt(0)" ::: "memory");
  __builtin_amdgcn_s_barrier();
  __builtin_amdgcn_sched_barrier(0);
  attn_tile((nT - 1)*KVB, qminw, qmaxw, q_l, lr, lg, sK[buf], sV[buf], sPw,
            qf0, qf1, o, mrun, lrun);

  float inv = 1.0f / lrun;
  float i0 = __shfl(inv, 4*lg + 0);
  float i1 = __shfl(inv, 4*lg + 1);
  float i2 = __shfl(inv, 4*lg + 2);
  float i3 = __shfl(inv, 4*lg + 3);
  #pragma unroll
  for (int nd = 0; nd < 4; ++nd) {
    int d = nd*16 + lr;
    int t0 = q0 + w*16 + lg*4;
    bf16* yp = yatt + ((size_t)(b*Tz + t0))*Cz + h*Dz + d;
    yp[0*Cz]   = (bf16)(o[nd][0] * i0);
    yp[1*Cz]   = (bf16)(o[nd][1] * i1);
    yp[2*Cz]   = (bf16)(o[nd][2] * i2);
    yp[3*Cz]   = (bf16)(o[nd][3] * i3);
  }
}

// ---------------- launch ----------------
extern "C" void kernel_launch(void* const* d_in, const int* in_sizes, int n_in,
                              void* d_out, int out_size, void* d_ws, size_t ws_size,
                              hipStream_t stream) {
  const float* x      = (const float*)d_in[0];
  const float* w_attn = (const float*)d_in[1];
  const float* b_attn = (const float*)d_in[2];
  const float* w_proj = (const float*)d_in[3];
  const float* b_proj = (const float*)d_in[4];

  float* y    = (float*)d_out;
  float* kout = y + YSZ;
  float* vout = y + 2*YSZ;

  char* ws = (char*)d_ws;
  bf16* xb   = (bf16*)ws;                     // 25165824 B (reused as yatt)
  bf16* qws  = (bf16*)(ws + 25165824);        // 25165824 B
  bf16* kb   = (bf16*)(ws + 50331648);        // 25165824 B
  bf16* vtb  = (bf16*)(ws + 75497472);        // 25165824 B
  bf16* wtA  = (bf16*)(ws + 100663296);       // 3538944 B
  bf16* wtP  = (bf16*)(ws + 104202240);       // 1179648 B
  bf16* yatt = xb;

  prep_x<<<2048, 256, 0, stream>>>(x, xb);
  transpose_conv<<<dim3(N3/32, Cz/32), 256, 0, stream>>>(w_attn, wtA, Cz, N3);
  transpose_conv<<<dim3(Cz/32, Cz/32), 256, 0, stream>>>(w_proj, wtP, Cz, Cz);

  gemm128<0><<<dim3((Mz/128)*(N3/128)), 256, 0, stream>>>(
      xb, wtA, Cz, Mz/128, N3/128, b_attn, qws, kb, kout, vout, nullptr);

  vtrans<<<dim3(Tz/64, Bz*Hz), 256, 0, stream>>>(vout, vtb);

  attn128<<<dim3(Tz/64, Bz*Hz), 256, 0, stream>>>(qws, kb, vtb, yatt);

  gemm128<1><<<dim3((Mz/128)*(Cz/128)), 256, 0, stream>>>(
      yatt, wtP, Cz, Mz/128, Cz/128, b_proj, nullptr, nullptr, nullptr, nullptr, y);
}

// Round 6
// 396.474 us; speedup vs baseline: 1.6614x; 1.0495x over previous
//
#include <hip/hip_runtime.h>
#include <hip/hip_bf16.h>
#include <stdint.h>

#define Bz 8
#define Tz 2048
#define Cz 768
#define Hz 12
#define Dz 64
#define Mz (Bz*Tz)          // 16384
#define N3 (3*Cz)           // 2304
#define YSZ ((size_t)Mz*Cz) // 12582912

#define SCL 0.18033688011112042f  // log2(e) / sqrt(64)
#define KVB 64
#define QBLK 128

typedef __bf16 bf16;
typedef __attribute__((ext_vector_type(8))) bf16 bf16x8;
typedef __attribute__((ext_vector_type(4))) bf16 bf16x4;
typedef __attribute__((ext_vector_type(4))) float f32x4;

#define MFMA(A_,B_,C_) __builtin_amdgcn_mfma_f32_16x16x32_bf16(A_,B_,C_,0,0,0)

__device__ __forceinline__ void gll16(const void* g, void* l) {
  __builtin_amdgcn_global_load_lds(
      (const __attribute__((address_space(1))) void*)g,
      (__attribute__((address_space(3))) void*)l, 16, 0, 0);
}

// ---------------- prep: x fp32 -> bf16 ----------------
__global__ __launch_bounds__(256) void prep_x(const float* __restrict__ x,
                                              bf16* __restrict__ xb) {
  int i = blockIdx.x*blockDim.x + threadIdx.x;
  int stride = gridDim.x*blockDim.x;
  const float4* x4 = (const float4*)x;
  int n4 = (int)(YSZ/4);
  for (int j = i; j < n4; j += stride) {
    float4 f = x4[j];
    bf16x4 o = { (bf16)f.x, (bf16)f.y, (bf16)f.z, (bf16)f.w };
    *(bf16x4*)(xb + 4*(size_t)j) = o;
  }
}

// ---------------- prep: transpose+convert W [R][Ncol] f32 -> Wt [Ncol][R] bf16 ----------------
__global__ __launch_bounds__(256) void transpose_conv(const float* __restrict__ src,
                                                      bf16* __restrict__ dst,
                                                      int R, int Ncol) {
  __shared__ float tile[32][33];
  int bx = blockIdx.x, by = blockIdx.y;
  int tx = threadIdx.x & 31, ty = threadIdx.x >> 5;
  #pragma unroll
  for (int i = 0; i < 4; ++i)
    tile[ty + 8*i][tx] = src[(size_t)(by*32 + ty + 8*i)*Ncol + bx*32 + tx];
  __syncthreads();
  #pragma unroll
  for (int i = 0; i < 4; ++i)
    dst[(size_t)(bx*32 + ty + 8*i)*R + by*32 + tx] = (bf16)tile[tx][ty + 8*i];
}

// ---------------- V transpose: vout f32 [BH][T][D] -> vtb bf16 [BH][D][T] ----------------
__global__ __launch_bounds__(256) void vtrans(const float* __restrict__ v,
                                              bf16* __restrict__ vt) {
  __shared__ float tl[64][65];
  int tb = blockIdx.x, bh = blockIdx.y;
  const float* src = v + ((size_t)bh*Tz + tb*64)*Dz;
  int tr = threadIdx.x >> 4;
  int c4 = (threadIdx.x & 15)*4;
  #pragma unroll
  for (int i = 0; i < 4; ++i) {
    float4 f = *(const float4*)(src + (size_t)(i*16 + tr)*Dz + c4);
    tl[i*16 + tr][c4+0] = f.x; tl[i*16 + tr][c4+1] = f.y;
    tl[i*16 + tr][c4+2] = f.z; tl[i*16 + tr][c4+3] = f.w;
  }
  __syncthreads();
  bf16* dst = vt + (size_t)bh*Dz*Tz + tb*64;
  #pragma unroll
  for (int i = 0; i < 4; ++i) {
    int d = i*16 + tr;
    bf16x4 o = { (bf16)tl[c4+0][d], (bf16)tl[c4+1][d],
                 (bf16)tl[c4+2][d], (bf16)tl[c4+3][d] };
    *(bf16x4*)(dst + (size_t)d*Tz + c4) = o;
  }
}

// ---------------- GEMM: C[M,N] = A[M,K] * Bt[N,K]^T  (m97 structure) ----------------
template<int EPI>
__global__ __launch_bounds__(256) void gemm128(
    const bf16* __restrict__ A, const bf16* __restrict__ Bt,
    int Kdim, int Mtiles, int Ntiles,
    const float* __restrict__ bias,
    bf16* __restrict__ qws, bf16* __restrict__ kws,
    float* __restrict__ kout, float* __restrict__ vout,
    float* __restrict__ yout)
{
  __shared__ alignas(16) bf16 sA[128*32];
  __shared__ alignas(16) bf16 sB[128*32];
  int nwg = Mtiles*Ntiles;
  int bid = blockIdx.x;
  int cpx = nwg >> 3;
  int swz = (bid & 7)*cpx + (bid >> 3);
  int mtile = swz % Mtiles, ntile = swz / Mtiles;
  int tid = threadIdx.x, w = tid >> 6, l = tid & 63;
  int wr = w >> 1, wc = w & 1;
  const int rowBase = mtile*128, colBase = ntile*128;

  f32x4 acc[4][4] = {};

  int srow = w*32 + (l >> 2);
  int skoff = (l & 3)*8;
  const bf16* gA = A + (size_t)(rowBase + srow)*Kdim + skoff;
  const bf16* gB = Bt + (size_t)(colBase + srow)*Kdim + skoff;
  bf16* lA = sA + w*1024;
  bf16* lB = sB + w*1024;

  int lr = l & 15, lk = (l >> 4)*8;

  for (int k0 = 0; k0 < Kdim; k0 += 32) {
    gll16(gA,                   lA);
    gll16(gA + (size_t)16*Kdim, lA + 512);
    gll16(gB,                   lB);
    gll16(gB + (size_t)16*Kdim, lB + 512);
    gA += 32; gB += 32;
    __syncthreads();
    bf16x8 af[4], bfr[4];
    #pragma unroll
    for (int m = 0; m < 4; ++m)
      af[m] = *(const bf16x8*)(sA + (size_t)(wr*64 + m*16 + lr)*32 + lk);
    #pragma unroll
    for (int n = 0; n < 4; ++n)
      bfr[n] = *(const bf16x8*)(sB + (size_t)(wc*64 + n*16 + lr)*32 + lk);
    #pragma unroll
    for (int m = 0; m < 4; ++m)
      #pragma unroll
      for (int n = 0; n < 4; ++n)
        acc[m][n] = MFMA(af[m], bfr[n], acc[m][n]);
    __syncthreads();
  }

  #pragma unroll
  for (int m = 0; m < 4; ++m) {
    #pragma unroll
    for (int n = 0; n < 4; ++n) {
      int gcol = colBase + wc*64 + n*16 + lr;
      float bv = bias[gcol];
      #pragma unroll
      for (int r = 0; r < 4; ++r) {
        int grow = rowBase + wr*64 + m*16 + (l >> 4)*4 + r;
        float v = acc[m][n][r] + bv;
        if (EPI == 0) {
          int which = gcol / Cz;
          int within = gcol - which*Cz;
          int h = within >> 6, d = within & 63;
          size_t idx = (((size_t)(grow >> 11)*Hz + h)*Tz + (grow & 2047))*Dz + d;
          if (which == 0)      qws[idx] = (bf16)(v * SCL);   // pre-scale q
          else if (which == 1) { kout[idx] = v; kws[idx] = (bf16)v; }
          else                 vout[idx] = v;
        } else {
          yout[(size_t)grow*Cz + gcol] = v;
        }
      }
    }
  }
}

// ---------------- flash attention (causal), QBLK=128, 8 waves, KVB=64 ----------------
__device__ __forceinline__ void stageKV(const bf16* kgb, const bf16* vgb, int kv0,
                                        char* cK, char* cV, int tid, int w) {
  int off = tid*16;                 // 0..8191 over 512 threads
  int row = off >> 7, ch = (off >> 4) & 7;
  int sw = ((ch ^ (row & 7)) << 3);
  gll16(kgb + (size_t)(kv0 + row)*Dz + sw, cK + w*1024);
  gll16(vgb + (size_t)row*Tz + kv0 + sw,   cV + w*1024);
}

__device__ __forceinline__ void attn_tile(
    int kv0, int qminw, int qmaxw, int q_l, int lr, int lg,
    const char* cK, const char* cV, char* sPw,
    const bf16x8& qf0, const bf16x8& qf1,
    f32x4 (&o)[4], float& mrun, float& lrun)
{
  const f32x4 zf = {0.f, 0.f, 0.f, 0.f};
  f32x4 s[4];
  // S^T[kv][q] = K * Q^T (swapped): lane owns q=q_l, kv = kv0 + n*16 + 4*lg + r
  __builtin_amdgcn_s_setprio(1);
  #pragma unroll
  for (int n = 0; n < 4; ++n) {
    int kvb = kv0 + n*16;
    if (kvb <= qmaxw) {
      int row = n*16 + lr;
      int c0 = lg ^ (lr & 7);
      bf16x8 kf0 = *(const bf16x8*)(cK + row*128 + (c0 << 4));
      bf16x8 kf1 = *(const bf16x8*)(cK + row*128 + ((c0 ^ 4) << 4));
      f32x4 t = MFMA(kf0, qf0, zf);
      s[n] = MFMA(kf1, qf1, t);
    } else {
      s[n][0] = -1e30f; s[n][1] = -1e30f; s[n][2] = -1e30f; s[n][3] = -1e30f;
    }
  }
  __builtin_amdgcn_s_setprio(0);
  // causal mask (diag blocks only; scale pre-folded into Q)
  #pragma unroll
  for (int n = 0; n < 4; ++n) {
    int kvb = kv0 + n*16;
    if (kvb <= qmaxw && kvb + 15 > qminw) {
      #pragma unroll
      for (int r = 0; r < 4; ++r)
        s[n][r] = (kvb + 4*lg + r <= q_l) ? s[n][r] : -1e30f;
    }
  }
  // in-lane max tree + 2 shfl
  f32x4 a0;
  #pragma unroll
  for (int r = 0; r < 4; ++r)
    a0[r] = fmaxf(fmaxf(s[0][r], s[1][r]), fmaxf(s[2][r], s[3][r]));
  float mx = fmaxf(fmaxf(a0[0], a0[1]), fmaxf(a0[2], a0[3]));
  mx = fmaxf(mx, __shfl_xor(mx, 16));
  mx = fmaxf(mx, __shfl_xor(mx, 32));

  bool skip = __all(mx <= mrun + 8.0f);
  float corr = 1.0f;
  if (!skip) {
    float mnew = fmaxf(mrun, mx);
    corr = exp2f(mrun - mnew);
    mrun = mnew;
  }
  f32x4 acc4 = zf;
  #pragma unroll
  for (int n = 0; n < 4; ++n) {
    #pragma unroll
    for (int r = 0; r < 4; ++r) {
      float e = exp2f(s[n][r] - mrun);
      s[n][r] = e;
      acc4[r] += e;
    }
  }
  float rs = (acc4[0] + acc4[1]) + (acc4[2] + acc4[3]);
  rs += __shfl_xor(rs, 16);
  rs += __shfl_xor(rs, 32);
  if (!skip) {
    lrun = lrun*corr + rs;
    float c0_ = __shfl(corr, 4*lg + 0);
    float c1_ = __shfl(corr, 4*lg + 1);
    float c2_ = __shfl(corr, 4*lg + 2);
    float c3_ = __shfl(corr, 4*lg + 3);
    #pragma unroll
    for (int nd = 0; nd < 4; ++nd) {
      o[nd][0] *= c0_; o[nd][1] *= c1_; o[nd][2] *= c2_; o[nd][3] *= c3_;
    }
  } else {
    lrun += rs;
  }
  // P store: [q=lr][kv] rows of 128B, chunk b ^= lr&7
  #pragma unroll
  for (int n = 0; n < 4; ++n) {
    bf16x4 pk = { (bf16)s[n][0], (bf16)s[n][1], (bf16)s[n][2], (bf16)s[n][3] };
    int b = n*2 + (lg >> 1);
    *(bf16x4*)(sPw + lr*128 + ((b ^ (lr & 7)) << 4) + ((lg & 1) << 3)) = pk;
  }
  // O += P V
  __builtin_amdgcn_s_setprio(1);
  #pragma unroll
  for (int kk = 0; kk < 2; ++kk) {
    if (kv0 + kk*32 <= qmaxw) {
      int cb = (kk*4 + lg) ^ (lr & 7);
      bf16x8 pf = *(const bf16x8*)(sPw + lr*128 + (cb << 4));
      #pragma unroll
      for (int nd = 0; nd < 4; ++nd) {
        bf16x8 vf = *(const bf16x8*)(cV + (nd*16 + lr)*128 + (cb << 4));
        o[nd] = MFMA(pf, vf, o[nd]);
      }
    }
  }
  __builtin_amdgcn_s_setprio(0);
}

__global__ __launch_bounds__(512, 6) void attn128(
    const bf16* __restrict__ qws, const bf16* __restrict__ kb,
    const bf16* __restrict__ vtb, bf16* __restrict__ yatt)
{
  __shared__ alignas(16) char sK[2][8192];   // [kv][d] 128B rows, chunk ^= row&7
  __shared__ alignas(16) char sV[2][8192];   // [d][t]  128B rows, chunk ^= row&7
  __shared__ alignas(16) char sP[8][2048];   // per-wave P^T
  int qb = gridDim.x - 1 - blockIdx.x;       // heavy tiles first
  int bh = blockIdx.y;
  int b = bh / Hz, h = bh - b*Hz;
  int tid = threadIdx.x, w = tid >> 6, l = tid & 63;
  int lr = l & 15, lg = l >> 4;
  const int q0 = qb*QBLK;
  const int qminw = q0 + w*16;
  const int qmaxw = qminw + 15;
  const int q_l = qminw + lr;

  const bf16* qbase = qws + ((size_t)bh*Tz + qminw + lr)*Dz + lg*8;
  bf16x8 qf0 = *(const bf16x8*)qbase;
  bf16x8 qf1 = *(const bf16x8*)(qbase + 32);

  f32x4 o[4] = {};
  float mrun = -1e30f, lrun = 0.f;

  const bf16* kgb = kb  + (size_t)bh*Tz*Dz;
  const bf16* vgb = vtb + (size_t)bh*Dz*Tz;
  char* sPw = sP[w];

  int nT = 2*qb + 2;
  stageKV(kgb, vgb, 0, sK[0], sV[0], tid, w);
  int buf = 0;
  for (int kt = 0; kt + 1 < nT; ++kt) {
    stageKV(kgb, vgb, (kt + 1)*KVB, sK[buf ^ 1], sV[buf ^ 1], tid, w);
    asm volatile("s_waitcnt vmcnt(2)" ::: "memory");
    __builtin_amdgcn_s_barrier();
    __builtin_amdgcn_sched_barrier(0);
    attn_tile(kt*KVB, qminw, qmaxw, q_l, lr, lg, sK[buf], sV[buf], sPw,
              qf0, qf1, o, mrun, lrun);
    asm volatile("s_waitcnt lgkmcnt(0)" ::: "memory");
    __builtin_amdgcn_s_barrier();
    __builtin_amdgcn_sched_barrier(0);
    buf ^= 1;
  }
  asm volatile("s_waitcnt vmcnt(0)" ::: "memory");
  __builtin_amdgcn_s_barrier();
  __builtin_amdgcn_sched_barrier(0);
  attn_tile((nT - 1)*KVB, qminw, qmaxw, q_l, lr, lg, sK[buf], sV[buf], sPw,
            qf0, qf1, o, mrun, lrun);

  float inv = 1.0f / lrun;
  float i0 = __shfl(inv, 4*lg + 0);
  float i1 = __shfl(inv, 4*lg + 1);
  float i2 = __shfl(inv, 4*lg + 2);
  float i3 = __shfl(inv, 4*lg + 3);
  #pragma unroll
  for (int nd = 0; nd < 4; ++nd) {
    int d = nd*16 + lr;
    int t0 = q0 + w*16 + lg*4;
    bf16* yp = yatt + ((size_t)(b*Tz + t0))*Cz + h*Dz + d;
    yp[0*Cz]   = (bf16)(o[nd][0] * i0);
    yp[1*Cz]   = (bf16)(o[nd][1] * i1);
    yp[2*Cz]   = (bf16)(o[nd][2] * i2);
    yp[3*Cz]   = (bf16)(o[nd][3] * i3);
  }
}

// ---------------- launch ----------------
extern "C" void kernel_launch(void* const* d_in, const int* in_sizes, int n_in,
                              void* d_out, int out_size, void* d_ws, size_t ws_size,
                              hipStream_t stream) {
  const float* x      = (const float*)d_in[0];
  const float* w_attn = (const float*)d_in[1];
  const float* b_attn = (const float*)d_in[2];
  const float* w_proj = (const float*)d_in[3];
  const float* b_proj = (const float*)d_in[4];

  float* y    = (float*)d_out;
  float* kout = y + YSZ;
  float* vout = y + 2*YSZ;

  char* ws = (char*)d_ws;
  bf16* xb   = (bf16*)ws;                     // 25165824 B (reused as yatt)
  bf16* qws  = (bf16*)(ws + 25165824);        // 25165824 B
  bf16* kb   = (bf16*)(ws + 50331648);        // 25165824 B
  bf16* vtb  = (bf16*)(ws + 75497472);        // 25165824 B
  bf16* wtA  = (bf16*)(ws + 100663296);       // 3538944 B
  bf16* wtP  = (bf16*)(ws + 104202240);       // 1179648 B
  bf16* yatt = xb;

  prep_x<<<2048, 256, 0, stream>>>(x, xb);
  transpose_conv<<<dim3(N3/32, Cz/32), 256, 0, stream>>>(w_attn, wtA, Cz, N3);
  transpose_conv<<<dim3(Cz/32, Cz/32), 256, 0, stream>>>(w_proj, wtP, Cz, Cz);

  gemm128<0><<<dim3((Mz/128)*(N3/128)), 256, 0, stream>>>(
      xb, wtA, Cz, Mz/128, N3/128, b_attn, qws, kb, kout, vout, nullptr);

  vtrans<<<dim3(Tz/64, Bz*Hz), 256, 0, stream>>>(vout, vtb);

  attn128<<<dim3(Tz/QBLK, Bz*Hz), 512, 0, stream>>>(qws, kb, vtb, yatt);

  gemm128<1><<<dim3((Mz/128)*(Cz/128)), 256, 0, stream>>>(
      yatt, wtP, Cz, Mz/128, Cz/128, b_proj, nullptr, nullptr, nullptr, nullptr, y);
}